// Round 1
// baseline (1830.682 us; speedup 1.0000x reference)
//
#include <hip/hip_runtime.h>

#define SEQ 2048
#define BATCH 2
#define NH 16
#define DM 1024
#define DEPTH 64
#define MROWS (BATCH * SEQ)   // 4096

// ---------------- fp32 GEMM + bias: C[M,1024] = A[M,1024] @ W[1024,1024] + bias ----------------
#define BM 128
#define BN 64
#define BK 16

__global__ __launch_bounds__(256) void gemm_bias_kernel(const float* __restrict__ A,
                                                        const float* __restrict__ W,
                                                        const float* __restrict__ bias,
                                                        float* __restrict__ C) {
    __shared__ float As[BK][BM + 1];   // [16][129] — pad kills store bank conflicts
    __shared__ float Bs[BK][BN];       // [16][64]

    const int t  = threadIdx.x;
    const int tx = t & 15;    // col group: cols tx*4 .. tx*4+3
    const int ty = t >> 4;    // row group: rows i*16+ty, i=0..7
    const int row0 = blockIdx.y * BM;
    const int col0 = blockIdx.x * BN;

    float acc[8][4];
#pragma unroll
    for (int i = 0; i < 8; ++i)
#pragma unroll
        for (int j = 0; j < 4; ++j) acc[i][j] = 0.f;

    const int arow = t >> 2;          // 0..63
    const int akg  = (t & 3) * 4;     // 0,4,8,12
    const int bkk  = t >> 4;          // 0..15
    const int bcol = (t & 15) * 4;    // 0..60

    for (int k0 = 0; k0 < DM; k0 += BK) {
#pragma unroll
        for (int half = 0; half < 2; ++half) {
            const int row = arow + half * 64;
            const float4 v = *(const float4*)&A[(size_t)(row0 + row) * DM + k0 + akg];
            As[akg + 0][row] = v.x;
            As[akg + 1][row] = v.y;
            As[akg + 2][row] = v.z;
            As[akg + 3][row] = v.w;
        }
        {
            const float4 w = *(const float4*)&W[(size_t)(k0 + bkk) * DM + col0 + bcol];
            *(float4*)&Bs[bkk][bcol] = w;
        }
        __syncthreads();
#pragma unroll
        for (int kk = 0; kk < BK; ++kk) {
            const float4 b4 = *(const float4*)&Bs[kk][tx * 4];
#pragma unroll
            for (int i = 0; i < 8; ++i) {
                const float a = As[kk][i * 16 + ty];
                acc[i][0] += a * b4.x;
                acc[i][1] += a * b4.y;
                acc[i][2] += a * b4.z;
                acc[i][3] += a * b4.w;
            }
        }
        __syncthreads();
    }

    const float4 bi = *(const float4*)&bias[col0 + tx * 4];
#pragma unroll
    for (int i = 0; i < 8; ++i) {
        const int row = row0 + i * 16 + ty;
        float4 o;
        o.x = acc[i][0] + bi.x;
        o.y = acc[i][1] + bi.y;
        o.z = acc[i][2] + bi.z;
        o.w = acc[i][3] + bi.w;
        *(float4*)&C[(size_t)row * DM + col0 + tx * 4] = o;
    }
}

// ---------------- fused attention: logits -> softmax -> attn write -> PV ----------------
// One block handles QB=8 query rows of one (b,h). 256 threads.
#define QB 8

__global__ __launch_bounds__(256) void attn_kernel(const float* __restrict__ Qb,
                                                   const float* __restrict__ Kb,
                                                   const float* __restrict__ Vb,
                                                   float* __restrict__ attn_out,
                                                   float* __restrict__ Ctx) {
    __shared__ float smem[QB * SEQ];   // 64 KB: qs/red early, then p-matrix, then ctx partials

    const int t  = threadIdx.x;
    const int qb = blockIdx.x & (SEQ / QB - 1);  // 0..255
    const int bh = blockIdx.x >> 8;              // 0..31
    const int b  = bh >> 4;
    const int h  = bh & 15;
    const int q0 = qb * QB;

    // base offset of this (b,h) panel inside [B,S,H*64] buffers; row j is at panel + j*DM
    const size_t panel = (size_t)b * SEQ * DM + (size_t)h * DEPTH;

    float* qs  = smem;          // [QB][DEPTH] = 512 floats (dead after phase 1)
    float* red = smem + 512;    // [256] (dead before p writes)

    // phase 0: load q rows, scaled by 1/sqrt(64)
    for (int idx = t; idx < QB * DEPTH; idx += 256) {
        const int r = idx >> 6, d = idx & 63;
        qs[r * DEPTH + d] = Qb[panel + (size_t)(q0 + r) * DM + d] * 0.125f;
    }
    __syncthreads();

    // phase 1: logits. acc[i][r] = logit for row q0+r, key j = i*256 + t
    float acc[8][QB];
#pragma unroll
    for (int i = 0; i < 8; ++i)
#pragma unroll
        for (int r = 0; r < QB; ++r) acc[i][r] = 0.f;

    const float* Kp = Kb + panel + (size_t)t * DM;
#pragma unroll 4
    for (int dd = 0; dd < DEPTH; dd += 4) {
        float4 q4[QB];
#pragma unroll
        for (int r = 0; r < QB; ++r) q4[r] = *(const float4*)&qs[r * DEPTH + dd];
#pragma unroll
        for (int i = 0; i < 8; ++i) {
            const float4 kv = *(const float4*)&Kp[(size_t)i * 256 * DM + dd];
#pragma unroll
            for (int r = 0; r < QB; ++r) {
                acc[i][r] += kv.x * q4[r].x + kv.y * q4[r].y + kv.z * q4[r].z + kv.w * q4[r].w;
            }
        }
    }
    __syncthreads();   // qs dead; red region safe to use

    // softmax over j, rows handled sequentially; values stay in registers
    float rinv[QB], mrow[QB];
    for (int r = 0; r < QB; ++r) {
        float m = -1e30f;
#pragma unroll
        for (int i = 0; i < 8; ++i) m = fmaxf(m, acc[i][r]);
        red[t] = m;
        __syncthreads();
        for (int s = 128; s > 0; s >>= 1) {
            if (t < s) red[t] = fmaxf(red[t], red[t + s]);
            __syncthreads();
        }
        const float mx = red[0];
        __syncthreads();
        float sum = 0.f;
#pragma unroll
        for (int i = 0; i < 8; ++i) sum += __expf(acc[i][r] - mx);
        red[t] = sum;
        __syncthreads();
        for (int s = 128; s > 0; s >>= 1) {
            if (t < s) red[t] += red[t + s];
            __syncthreads();
        }
        mrow[r] = mx;
        rinv[r] = 1.f / red[0];
        __syncthreads();
    }

    // write p into smem (as [QB][SEQ]) and attn rows to global
    float* attn_base = attn_out + ((size_t)bh * SEQ + q0) * SEQ;
#pragma unroll
    for (int r = 0; r < QB; ++r) {
#pragma unroll
        for (int i = 0; i < 8; ++i) {
            const float p = __expf(acc[i][r] - mrow[r]) * rinv[r];
            smem[r * SEQ + i * 256 + t] = p;
            attn_base[(size_t)r * SEQ + i * 256 + t] = p;
        }
    }
    __syncthreads();

    // phase 2: PV. thread: d4 = (t&15)*4 (4 depth cols), g = t>>4 (j stripe, stride 16)
    const int d4 = (t & 15) * 4;
    const int g  = t >> 4;
    const float* Vp = Vb + panel;
    float4 cacc[QB];
#pragma unroll
    for (int r = 0; r < QB; ++r) cacc[r] = make_float4(0.f, 0.f, 0.f, 0.f);

    for (int jj = 0; jj < SEQ / 16; ++jj) {
        const int j = jj * 16 + g;
        const float4 vv = *(const float4*)&Vp[(size_t)j * DM + d4];
#pragma unroll
        for (int r = 0; r < QB; ++r) {
            const float p = smem[r * SEQ + j];
            cacc[r].x += p * vv.x;
            cacc[r].y += p * vv.y;
            cacc[r].z += p * vv.z;
            cacc[r].w += p * vv.w;
        }
    }
    __syncthreads();   // everyone done reading p; reuse smem as ctx partials [16][QB][64]

#pragma unroll
    for (int r = 0; r < QB; ++r) {
        *(float4*)&smem[(g * QB + r) * DEPTH + d4] = cacc[r];
    }
    __syncthreads();

    for (int idx = t; idx < QB * DEPTH; idx += 256) {
        const int r = idx >> 6, d = idx & 63;
        float s = 0.f;
#pragma unroll
        for (int gg = 0; gg < 16; ++gg) s += smem[(gg * QB + r) * DEPTH + d];
        Ctx[panel + (size_t)(q0 + r) * DM + d] = s;
    }
}

extern "C" void kernel_launch(void* const* d_in, const int* in_sizes, int n_in,
                              void* d_out, int out_size, void* d_ws, size_t ws_size,
                              hipStream_t stream) {
    const float* x  = (const float*)d_in[0];
    const float* wq = (const float*)d_in[1];
    const float* bq = (const float*)d_in[2];
    const float* wk = (const float*)d_in[3];
    const float* bk = (const float*)d_in[4];
    const float* wv = (const float*)d_in[5];
    const float* bv = (const float*)d_in[6];
    const float* wo = (const float*)d_in[7];
    const float* bo = (const float*)d_in[8];

    float* out  = (float*)d_out;                          // [2,2048,1024]
    float* attn = out + (size_t)MROWS * DM;               // [2,16,2048,2048]

    float* ws = (float*)d_ws;
    float* Qb = ws;
    float* Kb = Qb + (size_t)MROWS * DM;
    float* Vb = Kb + (size_t)MROWS * DM;
    float* Cx = Vb + (size_t)MROWS * DM;

    const dim3 gblk(DM / BN, MROWS / BM);   // (16, 32)
    gemm_bias_kernel<<<gblk, 256, 0, stream>>>(x, wq, bq, Qb);
    gemm_bias_kernel<<<gblk, 256, 0, stream>>>(x, wk, bk, Kb);
    gemm_bias_kernel<<<gblk, 256, 0, stream>>>(x, wv, bv, Vb);

    attn_kernel<<<dim3(BATCH * NH * SEQ / QB), 256, 0, stream>>>(Qb, Kb, Vb, attn, Cx);

    gemm_bias_kernel<<<gblk, 256, 0, stream>>>(Cx, wo, bo, out);
}